// Round 5
// baseline (410.561 us; speedup 1.0000x reference)
//
#include <hip/hip_runtime.h>
#include <math.h>

#define BB 512
#define NN 1000
#define DD 128
#define HH 8
#define TILE 125   // 8 tiles of 125 rows

__device__ __forceinline__ bool mask_feasible(const void* mask, int flag, int idx) {
    if (flag == 1) return ((const int*)mask)[idx] != 0;
    if (flag == 2) return ((const float*)mask)[idx] != 0.0f;
    return ((const unsigned char*)mask)[idx] != 0;
}

__device__ __forceinline__ float rdl(float v, int srclane) {
    return __int_as_float(__builtin_amdgcn_readlane(__float_as_int(v), srclane));
}

// Detect action_mask storage dtype from its first 64 32-bit words.
__global__ void k0_detect(const unsigned int* __restrict__ m, int* __restrict__ flag) {
    int t = threadIdx.x;
    unsigned int w = m[t];
    unsigned long long bi = __ballot(w <= 1u);
    unsigned long long bf = __ballot(w == 0u || w == 0x3F800000u);
    if (t == 0) {
        int f = 0;
        if (bi == ~0ull) f = 1;
        else if (bf == ~0ull) f = 2;
        *flag = f;
    }
}

// One block per b: mean -> q -> Afold -> flash(compat/softmax/wemb) -> glimpse -> logits.
// 512 threads (8 waves), ~74 KB LDS -> 2 blocks/CU -> 16 waves/CU.
__global__ __launch_bounds__(512, 4) void kMega(
    const float* __restrict__ emb, const float* __restrict__ ctx,
    const float* __restrict__ W_fixed, const float* __restrict__ W_step,
    const float* __restrict__ W_node, const float* __restrict__ W_out,
    const void* __restrict__ mask, const int* __restrict__ flagp,
    float* __restrict__ out) {
    int b = blockIdx.x, t = threadIdx.x;
    int flag = *flagp;
    int wave = t >> 6, lane = t & 63;
    int hq = (t >> 7) * 2;               // 4 groups of 128 threads: heads {hq, hq+1}
    int n = t & 127;                     // compat row (valid < TILE)
    int c4 = t & 31, jr = t >> 5;        // accumulate role (jr 0..15)

    __shared__ float4 tile4[128][32];    // 64 KB: staged tile (swizzled); reused as mean-red and wemb-red
    __shared__ float cbuf[HH][DD];       // 4 KB: compat/p (transposed); reused as wemb[8][128]
    __shared__ float small[1536];        // 6 KB: mean[0:128] q[128:256] cld[256:512] Af[512:1536]; tail: hl/gl/g2
    __shared__ float mrun[8], zrun[8], scale_s[8], mnew_s[8];
    __shared__ float2 wmax2[8], zstage[8];

    const float4* embB4 = (const float4*)(emb + (size_t)b * NN * DD);
    const int mbase = b * NN;

    // ---- phase 0: mean over N (the only HBM-cold pass over this block's rows) ----
    {
        float4 acc = make_float4(0.f, 0.f, 0.f, 0.f);
        for (int nn = jr; nn < NN; nn += 16) {
            float4 v = embB4[nn * 32 + c4];
            acc.x += v.x; acc.y += v.y; acc.z += v.z; acc.w += v.w;
        }
        float4* red = (float4*)tile4;
        red[t] = acc;
        __syncthreads();
        for (int s = 8; s >= 1; s >>= 1) {
            if (jr < s) {
                float4 o = red[t + s * 32], m = red[t];
                m.x += o.x; m.y += o.y; m.z += o.z; m.w += o.w;
                red[t] = m;
            }
            __syncthreads();
        }
        if (t < 32) {
            float4 m = red[t];
            const float inv = 1.0f / (float)NN;
            float4 r = {m.x * inv, m.y * inv, m.z * inv, m.w * inv};
            ((float4*)&small[0])[t] = r;
        }
        if (t >= 256) small[t] = ctx[b * 2 * DD + (t - 256)];
    }
    __syncthreads();
    // ---- phase 1: q = mean@W_fixed + ctx@W_step ----
    if (t < 128) {
        float a = 0.f;
        for (int c = 0; c < DD; ++c)     a += small[c] * W_fixed[c * DD + t];
        for (int c = 0; c < 2 * DD; ++c) a += small[256 + c] * W_step[c * DD + t];
        small[128 + t] = a;
    }
    __syncthreads();
    // ---- phase 2: Afold[c][h] = 0.25 * sum_d Wk[c, h*16+d] q[h*16+d] ----
    if (t < 128) {
        const float* wrow = W_node + (size_t)t * 384;   // Wk cols [0,128)
        for (int h = 0; h < HH; ++h) {
            float a = 0.f;
#pragma unroll
            for (int d0 = 0; d0 < 16; ++d0) a += wrow[h * 16 + d0] * small[128 + h * 16 + d0];
            small[512 + t * 8 + h] = 0.25f * a;
        }
    }
    if (t < 8) { mrun[t] = -INFINITY; zrun[t] = 0.f; }
    __syncthreads();
    // A lane-distributed regs: lane l holds A[l][.], A[64+l][.] for 2 heads
    float a0l = small[512 + lane * 8 + hq],        a1l = small[512 + lane * 8 + hq + 1];
    float a0h = small[512 + (64 + lane) * 8 + hq], a1h = small[512 + (64 + lane) * 8 + hq + 1];

    float4 wacc[8];
#pragma unroll
    for (int h = 0; h < HH; ++h) wacc[h] = make_float4(0.f, 0.f, 0.f, 0.f);

    // ---- flash loop over 8 tiles ----
    for (int tile = 0; tile < 8; ++tile) {
        int n0 = tile * TILE;
        // stage tile -> LDS (L2/L3-warm after phase 0), swizzled columns
#pragma unroll
        for (int idx = 0; idx < 8; ++idx) {
            int i = t + idx * 512;
            if (i < TILE * 32) {
                int r = i >> 5, c = i & 31;
                tile4[r][c ^ (r & 31)] = embB4[n0 * 32 + i];
            }
        }
        __syncthreads();
        // compat: 2 heads per thread
        float2 cv = make_float2(-INFINITY, -INFINITY);
        if (n < TILE) {
            int sw = n & 31;
            float sx = 0.f, sy = 0.f;
#pragma unroll
            for (int k = 0; k < 16; ++k) {          // c = 0..63
                float4 e = tile4[n][k ^ sw];
                int c = k * 4;
                sx += e.x * rdl(a0l, c) + e.y * rdl(a0l, c + 1) + e.z * rdl(a0l, c + 2) + e.w * rdl(a0l, c + 3);
                sy += e.x * rdl(a1l, c) + e.y * rdl(a1l, c + 1) + e.z * rdl(a1l, c + 2) + e.w * rdl(a1l, c + 3);
            }
#pragma unroll
            for (int k = 16; k < 32; ++k) {         // c = 64..127
                float4 e = tile4[n][k ^ sw];
                int c = k * 4 - 64;
                sx += e.x * rdl(a0h, c) + e.y * rdl(a0h, c + 1) + e.z * rdl(a0h, c + 2) + e.w * rdl(a0h, c + 3);
                sy += e.x * rdl(a1h, c) + e.y * rdl(a1h, c + 1) + e.z * rdl(a1h, c + 2) + e.w * rdl(a1h, c + 3);
            }
            if (mask_feasible(mask, flag, mbase + n0 + n)) { cv.x = sx; cv.y = sy; }
            cbuf[hq][n] = cv.x;
            cbuf[hq + 1][n] = cv.y;
        }
        // per-wave butterfly max (idle rows hold -inf)
        {
            float2 wm = cv;
#pragma unroll
            for (int off = 1; off < 64; off <<= 1) {
                wm.x = fmaxf(wm.x, __shfl_xor(wm.x, off));
                wm.y = fmaxf(wm.y, __shfl_xor(wm.y, off));
            }
            if (lane == 0) wmax2[wave] = wm;
        }
        __syncthreads();
        // online max/scale update
        if (t < 8) {
            int w0 = (t >> 1) * 2;
            float m = (t & 1) ? fmaxf(wmax2[w0].y, wmax2[w0 + 1].y)
                              : fmaxf(wmax2[w0].x, wmax2[w0 + 1].x);
            float mold = mrun[t];
            float mn = fmaxf(mold, m);
            mnew_s[t] = mn;
            scale_s[t] = (mn == -INFINITY) ? 1.0f : __expf(mold - mn);
            mrun[t] = mn;
        }
        __syncthreads();
        // p = exp(cv - mnew), wave z-sum, rescale wacc
        {
            float m0 = mnew_s[hq], m1 = mnew_s[hq + 1];
            float2 p = make_float2(0.f, 0.f);
            if (n < TILE) {
                p.x = (cv.x == -INFINITY) ? 0.f : __expf(cv.x - m0);
                p.y = (cv.y == -INFINITY) ? 0.f : __expf(cv.y - m1);
                cbuf[hq][n] = p.x;
                cbuf[hq + 1][n] = p.y;
            }
#pragma unroll
            for (int off = 1; off < 64; off <<= 1) {
                p.x += __shfl_xor(p.x, off);
                p.y += __shfl_xor(p.y, off);
            }
            if (lane == 0) zstage[wave] = p;
            float sc0 = scale_s[0], sc1 = scale_s[1], sc2 = scale_s[2], sc3 = scale_s[3];
            float sc4 = scale_s[4], sc5 = scale_s[5], sc6 = scale_s[6], sc7 = scale_s[7];
            wacc[0].x *= sc0; wacc[0].y *= sc0; wacc[0].z *= sc0; wacc[0].w *= sc0;
            wacc[1].x *= sc1; wacc[1].y *= sc1; wacc[1].z *= sc1; wacc[1].w *= sc1;
            wacc[2].x *= sc2; wacc[2].y *= sc2; wacc[2].z *= sc2; wacc[2].w *= sc2;
            wacc[3].x *= sc3; wacc[3].y *= sc3; wacc[3].z *= sc3; wacc[3].w *= sc3;
            wacc[4].x *= sc4; wacc[4].y *= sc4; wacc[4].z *= sc4; wacc[4].w *= sc4;
            wacc[5].x *= sc5; wacc[5].y *= sc5; wacc[5].z *= sc5; wacc[5].w *= sc5;
            wacc[6].x *= sc6; wacc[6].y *= sc6; wacc[6].z *= sc6; wacc[6].w *= sc6;
            wacc[7].x *= sc7; wacc[7].y *= sc7; wacc[7].z *= sc7; wacc[7].w *= sc7;
        }
        __syncthreads();
        // zrun update + wemb accumulate from LDS tile
        if (t < 8) {
            int w0 = (t >> 1) * 2;
            float zn = (t & 1) ? (zstage[w0].y + zstage[w0 + 1].y)
                               : (zstage[w0].x + zstage[w0 + 1].x);
            zrun[t] = zrun[t] * scale_s[t] + zn;
        }
        for (int nn = jr; nn < TILE; nn += 16) {
            float4 e = tile4[nn][c4 ^ (nn & 31)];
            float p0 = cbuf[0][nn], p1 = cbuf[1][nn], p2 = cbuf[2][nn], p3 = cbuf[3][nn];
            float p4 = cbuf[4][nn], p5 = cbuf[5][nn], p6 = cbuf[6][nn], p7 = cbuf[7][nn];
            wacc[0].x += p0 * e.x; wacc[0].y += p0 * e.y; wacc[0].z += p0 * e.z; wacc[0].w += p0 * e.w;
            wacc[1].x += p1 * e.x; wacc[1].y += p1 * e.y; wacc[1].z += p1 * e.z; wacc[1].w += p1 * e.w;
            wacc[2].x += p2 * e.x; wacc[2].y += p2 * e.y; wacc[2].z += p2 * e.z; wacc[2].w += p2 * e.w;
            wacc[3].x += p3 * e.x; wacc[3].y += p3 * e.y; wacc[3].z += p3 * e.z; wacc[3].w += p3 * e.w;
            wacc[4].x += p4 * e.x; wacc[4].y += p4 * e.y; wacc[4].z += p4 * e.z; wacc[4].w += p4 * e.w;
            wacc[5].x += p5 * e.x; wacc[5].y += p5 * e.y; wacc[5].z += p5 * e.z; wacc[5].w += p5 * e.w;
            wacc[6].x += p6 * e.x; wacc[6].y += p6 * e.y; wacc[6].z += p6 * e.z; wacc[6].w += p6 * e.w;
            wacc[7].x += p7 * e.x; wacc[7].y += p7 * e.y; wacc[7].z += p7 * e.z; wacc[7].w += p7 * e.w;
        }
        __syncthreads();   // tile4/cbuf dead before next stage
    }
    // ---- j-reduce wemb partials (tile4 as scratch [16][32][8] f4), normalize -> cbuf = wemb[8][128] ----
    {
        float4* red = (float4*)tile4;
#pragma unroll
        for (int h = 0; h < HH; ++h) red[(jr * 32 + c4) * 8 + h] = wacc[h];
        __syncthreads();
        if (t < 256) {
            int cc = t >> 3, hh = t & 7;
            float4 s = make_float4(0.f, 0.f, 0.f, 0.f);
#pragma unroll
            for (int jj = 0; jj < 16; ++jj) {
                float4 v = red[(jj * 32 + cc) * 8 + hh];
                s.x += v.x; s.y += v.y; s.z += v.z; s.w += v.w;
            }
            float inv = 1.0f / zrun[hh];
            s.x *= inv; s.y *= inv; s.z *= inv; s.w *= inv;
            ((float4*)&cbuf[hh][0])[cc] = s;
        }
    }
    __syncthreads();
    // ---- glimpse tail ----
    if (t < 128) {
        int h = t >> 4;
        float a = 0.f;
        for (int c = 0; c < DD; ++c) a += cbuf[h][c] * W_node[(size_t)c * 384 + 128 + t];
        small[t] = a;                          // hl
    }
    __syncthreads();
    if (t < 128) {
        float g = 0.f;
        for (int k = 0; k < DD; ++k) g += small[k] * W_out[k * DD + t];
        small[128 + t] = g;                    // gl
    }
    __syncthreads();
    if (t < 128) {
        float a3 = 0.f;
        const float* wr = W_node + (size_t)t * 384 + 256;   // Wl row t
        for (int d = 0; d < DD; ++d) a3 += wr[d] * small[128 + d];
        small[256 + t] = a3;                   // g2
    }
    __syncthreads();
    // ---- logits tail: out[b,n] = masked ? -1e30 : 10*tanh(emb.g2/sqrt(128)) ----
    const float4* g2v = (const float4*)&small[256];
    for (int r = t; r < NN; r += 512) {
        const float4* row = embB4 + (size_t)r * 32;
        float acc = 0.f;
#pragma unroll 8
        for (int k = 0; k < 32; ++k) {
            float4 e = row[k], g = g2v[k];
            acc += e.x * g.x + e.y * g.y + e.z * g.z + e.w * g.w;
        }
        bool feas = mask_feasible(mask, flag, mbase + r);
        out[(size_t)mbase + r] = feas ? (10.0f * tanhf(acc * 0.08838834764831845f)) : -1.0e30f;
    }
}

extern "C" void kernel_launch(void* const* d_in, const int* in_sizes, int n_in,
                              void* d_out, int out_size, void* d_ws, size_t ws_size,
                              hipStream_t stream) {
    (void)in_sizes; (void)n_in; (void)out_size; (void)ws_size;
    const float* emb     = (const float*)d_in[0];
    const float* ctx     = (const float*)d_in[1];
    const float* W_node  = (const float*)d_in[2];
    const float* W_fixed = (const float*)d_in[3];
    const float* W_step  = (const float*)d_in[4];
    const float* W_out   = (const float*)d_in[5];
    const void*  mask    = d_in[6];
    float* out = (float*)d_out;

    int* flag = (int*)d_ws;
    k0_detect<<<1, 64, 0, stream>>>((const unsigned int*)mask, flag);
    kMega<<<BB, 512, 0, stream>>>(emb, ctx, W_fixed, W_step, W_node, W_out, mask, flag, out);
}

// Round 6
// 301.837 us; speedup vs baseline: 1.3602x; 1.3602x over previous
//
#include <hip/hip_runtime.h>
#include <math.h>

#define BB 512
#define NN 1000
#define DD 128
#define HH 8
#define TILE 64    // 16 tiles (last has 40 rows)
#define NT 16

// ws layout: flag@0 (4B) | Afold@4096: [B][128][8] f32 (2 MB)
#define WS_AFOLD 4096

__device__ __forceinline__ bool mask_feasible(const void* mask, int flag, int idx) {
    if (flag == 1) return ((const int*)mask)[idx] != 0;
    if (flag == 2) return ((const float*)mask)[idx] != 0.0f;
    return ((const unsigned char*)mask)[idx] != 0;
}

__device__ __forceinline__ float rdl(float v, int srclane) {
    return __int_as_float(__builtin_amdgcn_readlane(__float_as_int(v), srclane));
}

// Detect action_mask storage dtype from its first 64 32-bit words.
__global__ void k0_detect(const unsigned int* __restrict__ m, int* __restrict__ flag) {
    int t = threadIdx.x;
    unsigned int w = m[t];
    unsigned long long bi = __ballot(w <= 1u);
    unsigned long long bf = __ballot(w == 0u || w == 0x3F800000u);
    if (t == 0) {
        int f = 0;
        if (bi == ~0ull) f = 1;
        else if (bf == ~0ull) f = 2;
        *flag = f;
    }
}

// Fused: mean over N -> q = mean@W_fixed + ctx@W_step -> Afold[c][h]
// NOTE: no 2nd launch_bounds arg — round 5 showed it acts as min-BLOCKS/CU
// on this stack and strangles VGPRs (64) causing 518 MB of scratch spill.
__global__ __launch_bounds__(512) void kA_meanfold(
    const float* __restrict__ emb, const float* __restrict__ ctx,
    const float* __restrict__ W_fixed, const float* __restrict__ W_step,
    const float* __restrict__ W_node, float* __restrict__ Afold) {
    int b = blockIdx.x, t = threadIdx.x;
    __shared__ float4 red[512];
    __shared__ float mean_s[DD], cld[2 * DD], qlds[DD];
    int q4 = t & 31, j = t >> 5;
    const float4* e4 = (const float4*)(emb + (size_t)b * NN * DD);
    float4 acc = {0.f, 0.f, 0.f, 0.f};
    for (int n = j; n < NN; n += 16) {
        float4 v = e4[n * 32 + q4];
        acc.x += v.x; acc.y += v.y; acc.z += v.z; acc.w += v.w;
    }
    red[t] = acc;
    __syncthreads();
    for (int s = 8; s >= 1; s >>= 1) {
        if (j < s) {
            float4 o = red[t + s * 32], m = red[t];
            m.x += o.x; m.y += o.y; m.z += o.z; m.w += o.w;
            red[t] = m;
        }
        __syncthreads();
    }
    if (t < 32) {
        float4 m = red[t];
        const float inv = 1.0f / (float)NN;
        float4 r = {m.x * inv, m.y * inv, m.z * inv, m.w * inv};
        ((float4*)mean_s)[t] = r;
    }
    if (t < 256) cld[t] = ctx[b * 2 * DD + t];
    __syncthreads();
    if (t < 128) {
        float a = 0.f;
        for (int c = 0; c < DD; ++c)     a += mean_s[c] * W_fixed[c * DD + t];
        for (int c = 0; c < 2 * DD; ++c) a += cld[c] * W_step[c * DD + t];
        qlds[t] = a;
    }
    __syncthreads();
    if (t < 128) {
        int c = t;
        const float* wrow = W_node + (size_t)c * 3 * DD;   // Wk cols [0,128)
        float* Ab = Afold + (size_t)b * 1024;
        for (int h = 0; h < HH; ++h) {
            float a = 0.f;
#pragma unroll
            for (int d0 = 0; d0 < 16; ++d0) a += wrow[h * 16 + d0] * qlds[h * 16 + d0];
            Ab[c * 8 + h] = 0.25f * a;   // 1/sqrt(dk) folded
        }
    }
}

// Flash + glimpse + logits. 512 threads = 8 waves; wave w owns head w.
// Online softmax is wave-local (registers + butterflies); 2 barriers/tile.
__global__ __launch_bounds__(512) void kB_flash(
    const float* __restrict__ emb, const float* __restrict__ Afold,
    const void* __restrict__ mask, const int* __restrict__ flagp,
    const float* __restrict__ W_node, const float* __restrict__ W_out,
    float* __restrict__ out) {
    int b = blockIdx.x, t = threadIdx.x;
    int flag = *flagp;
    int wave = t >> 6, lane = t & 63;     // wave = head
    int c4 = lane & 31, jh = lane >> 5;   // accumulate role

    __shared__ float4 tile4[TILE][32];    // 32 KB staged emb tile, XOR-swizzled cols
    __shared__ float wemb_s[HH][DD];      // 4 KB
    __shared__ float small[3 * DD];       // hl / gl / g2

    // A lane-distributed: lane l holds A[l][wave], A[64+l][wave]
    const float* Ab = Afold + (size_t)b * 1024;
    float a0l = Ab[lane * 8 + wave];
    float a0h = Ab[(64 + lane) * 8 + wave];

    float4 wacc = make_float4(0.f, 0.f, 0.f, 0.f);
    float mrun = -INFINITY, zrun = 0.f;

    const float4* embB4 = (const float4*)(emb + (size_t)b * NN * DD);
    const int mbase = b * NN;

    for (int tile = 0; tile < NT; ++tile) {
        int n0 = tile * TILE;
        int rows = (NN - n0 < TILE) ? (NN - n0) : TILE;
        // ---- stage tile -> LDS (coalesced, swizzled) ----
#pragma unroll
        for (int idx = 0; idx < 4; ++idx) {
            int i = t + idx * 512;
            int r = i >> 5, c = i & 31;
            if (r < rows) tile4[r][c ^ (r & 31)] = embB4[n0 * 32 + i];
        }
        __syncthreads();
        // ---- compat: row = lane, head = wave ----
        float cv = -INFINITY;
        if (lane < rows) {
            int sw = lane & 31;
            float s = 0.f;
#pragma unroll
            for (int k = 0; k < 16; ++k) {          // c = 0..63
                float4 e = tile4[lane][k ^ sw];
                int c = k * 4;
                s += e.x * rdl(a0l, c) + e.y * rdl(a0l, c + 1) + e.z * rdl(a0l, c + 2) + e.w * rdl(a0l, c + 3);
            }
#pragma unroll
            for (int k = 16; k < 32; ++k) {         // c = 64..127
                float4 e = tile4[lane][k ^ sw];
                int c = k * 4 - 64;
                s += e.x * rdl(a0h, c) + e.y * rdl(a0h, c + 1) + e.z * rdl(a0h, c + 2) + e.w * rdl(a0h, c + 3);
            }
            if (mask_feasible(mask, flag, mbase + n0 + lane)) cv = s;
        }
        // ---- wave-local online softmax ----
        float m = cv;
#pragma unroll
        for (int off = 1; off < 64; off <<= 1) m = fmaxf(m, __shfl_xor(m, off));
        float mn = fmaxf(mrun, m);
        float scale = (mn == -INFINITY) ? 1.0f : __expf(mrun - mn);
        mrun = mn;
        float p = (cv == -INFINITY) ? 0.f : __expf(cv - mn);
        float z = p;
#pragma unroll
        for (int off = 1; off < 64; off <<= 1) z += __shfl_xor(z, off);
        zrun = zrun * scale + z;
        wacc.x *= scale; wacc.y *= scale; wacc.z *= scale; wacc.w *= scale;
        // ---- accumulate wemb for own head: cols c4, rows jh::2 ----
        for (int nn = jh; nn < rows; nn += 2) {
            float4 e = tile4[nn][c4 ^ (nn & 31)];
            float pv = __shfl(p, nn);               // p of row nn (bpermute)
            wacc.x += pv * e.x; wacc.y += pv * e.y; wacc.z += pv * e.z; wacc.w += pv * e.w;
        }
        __syncthreads();   // tile4 dead before next stage
    }
    // ---- combine jh halves, normalize, write wemb ----
    wacc.x += __shfl_xor(wacc.x, 32);
    wacc.y += __shfl_xor(wacc.y, 32);
    wacc.z += __shfl_xor(wacc.z, 32);
    wacc.w += __shfl_xor(wacc.w, 32);
    {
        float inv = 1.0f / zrun;
        if (lane < 32) {
            wemb_s[wave][c4 * 4 + 0] = wacc.x * inv;
            wemb_s[wave][c4 * 4 + 1] = wacc.y * inv;
            wemb_s[wave][c4 * 4 + 2] = wacc.z * inv;
            wemb_s[wave][c4 * 4 + 3] = wacc.w * inv;
        }
    }
    __syncthreads();
    // ---- glimpse tail ----
    if (t < 128) {
        int h = t >> 4;
        float a = 0.f;
        for (int c = 0; c < DD; ++c) a += wemb_s[h][c] * W_node[(size_t)c * 384 + 128 + t];
        small[t] = a;                          // hl
    }
    __syncthreads();
    if (t < 128) {
        float g = 0.f;
        for (int k = 0; k < DD; ++k) g += small[k] * W_out[k * DD + t];
        small[128 + t] = g;                    // gl
    }
    __syncthreads();
    if (t < 128) {
        float a3 = 0.f;
        const float* wr = W_node + (size_t)t * 384 + 256;   // Wl row t
        for (int d = 0; d < DD; ++d) a3 += wr[d] * small[128 + d];
        small[256 + t] = a3;                   // g2
    }
    __syncthreads();
    // ---- logits tail ----
    const float4* g2v = (const float4*)&small[256];
    for (int r = t; r < NN; r += 512) {
        const float4* row = embB4 + (size_t)r * 32;
        float acc = 0.f;
#pragma unroll 8
        for (int k = 0; k < 32; ++k) {
            float4 e = row[k], g = g2v[k];
            acc += e.x * g.x + e.y * g.y + e.z * g.z + e.w * g.w;
        }
        bool feas = mask_feasible(mask, flag, mbase + r);
        out[(size_t)mbase + r] = feas ? (10.0f * tanhf(acc * 0.08838834764831845f)) : -1.0e30f;
    }
}

extern "C" void kernel_launch(void* const* d_in, const int* in_sizes, int n_in,
                              void* d_out, int out_size, void* d_ws, size_t ws_size,
                              hipStream_t stream) {
    (void)in_sizes; (void)n_in; (void)out_size; (void)ws_size;
    const float* emb     = (const float*)d_in[0];
    const float* ctx     = (const float*)d_in[1];
    const float* W_node  = (const float*)d_in[2];
    const float* W_fixed = (const float*)d_in[3];
    const float* W_step  = (const float*)d_in[4];
    const float* W_out   = (const float*)d_in[5];
    const void*  mask    = d_in[6];
    float* out = (float*)d_out;

    char* ws = (char*)d_ws;
    int*   flag  = (int*)(ws + 0);
    float* Afold = (float*)(ws + WS_AFOLD);

    k0_detect<<<1, 64, 0, stream>>>((const unsigned int*)mask, flag);
    kA_meanfold<<<BB, 512, 0, stream>>>(emb, ctx, W_fixed, W_step, W_node, Afold);
    kB_flash<<<BB, 512, 0, stream>>>(emb, Afold, mask, flag, W_node, W_out, out);
}

// Round 8
// 248.870 us; speedup vs baseline: 1.6497x; 1.2128x over previous
//
#include <hip/hip_runtime.h>
#include <math.h>

#define BB 512
#define NN 1000
#define DD 128
#define HH 8

// ws layout: flag@0 (4B) | Afold@4096: [B][128][8] f32 (2 MB)
#define WS_AFOLD 4096

__device__ __forceinline__ bool mask_feasible(const void* mask, int flag, int idx) {
    if (flag == 1) return ((const int*)mask)[idx] != 0;
    if (flag == 2) return ((const float*)mask)[idx] != 0.0f;
    return ((const unsigned char*)mask)[idx] != 0;
}

__device__ __forceinline__ float rdl(float v, int srclane) {
    return __int_as_float(__builtin_amdgcn_readlane(__float_as_int(v), srclane));
}

// Detect action_mask storage dtype from its first 64 32-bit words.
__global__ void k0_detect(const unsigned int* __restrict__ m, int* __restrict__ flag) {
    int t = threadIdx.x;
    unsigned int w = m[t];
    unsigned long long bi = __ballot(w <= 1u);
    unsigned long long bf = __ballot(w == 0u || w == 0x3F800000u);
    if (t == 0) {
        int f = 0;
        if (bi == ~0ull) f = 1;
        else if (bf == ~0ull) f = 2;
        *flag = f;
    }
}

// Fused: mean over N -> q = mean@W_fixed + ctx@W_step -> Afold[c][h]
// NOTE: no 2nd launch_bounds arg — round 5 showed it acts as min-BLOCKS/CU
// here and strangled VGPRs to 64, causing 518 MB of scratch spill.
__global__ __launch_bounds__(512) void kA_meanfold(
    const float* __restrict__ emb, const float* __restrict__ ctx,
    const float* __restrict__ W_fixed, const float* __restrict__ W_step,
    const float* __restrict__ W_node, float* __restrict__ Afold) {
    int b = blockIdx.x, t = threadIdx.x;
    __shared__ float4 red[512];
    __shared__ float mean_s[DD], cld[2 * DD], qlds[DD];
    int q4 = t & 31, j = t >> 5;
    const float4* e4 = (const float4*)(emb + (size_t)b * NN * DD);
    float4 acc = {0.f, 0.f, 0.f, 0.f};
    for (int n = j; n < NN; n += 16) {
        float4 v = e4[n * 32 + q4];
        acc.x += v.x; acc.y += v.y; acc.z += v.z; acc.w += v.w;
    }
    red[t] = acc;
    __syncthreads();
    for (int s = 8; s >= 1; s >>= 1) {
        if (j < s) {
            float4 o = red[t + s * 32], m = red[t];
            m.x += o.x; m.y += o.y; m.z += o.z; m.w += o.w;
            red[t] = m;
        }
        __syncthreads();
    }
    if (t < 32) {
        float4 m = red[t];
        const float inv = 1.0f / (float)NN;
        float4 r = {m.x * inv, m.y * inv, m.z * inv, m.w * inv};
        ((float4*)mean_s)[t] = r;
    }
    if (t < 256) cld[t] = ctx[b * 2 * DD + t];
    __syncthreads();
    if (t < 128) {
        float a = 0.f;
        for (int c = 0; c < DD; ++c)     a += mean_s[c] * W_fixed[c * DD + t];
        for (int c = 0; c < 2 * DD; ++c) a += cld[c] * W_step[c * DD + t];
        qlds[t] = a;
    }
    __syncthreads();
    if (t < 128) {
        int c = t;
        const float* wrow = W_node + (size_t)c * 3 * DD;   // Wk cols [0,128)
        float* A2 = Afold + (size_t)b * 1024;
        for (int h = 0; h < HH; ++h) {
            float a = 0.f;
#pragma unroll
            for (int d0 = 0; d0 < 16; ++d0) a += wrow[h * 16 + d0] * qlds[h * 16 + d0];
            A2[c * 8 + h] = 0.25f * a;   // 1/sqrt(dk) folded
        }
    }
}

// Full-row softmax variant: compat(global) -> softmax(LDS) -> accumulate(global,
// L2/L3-warm) -> glimpse -> logits. One block of 256 per b; ~8 barriers total.
__global__ __launch_bounds__(256) void kB_attn(
    const float* __restrict__ emb, const float* __restrict__ Afold,
    const void* __restrict__ mask, const int* __restrict__ flagp,
    const float* __restrict__ W_node, const float* __restrict__ W_out,
    float* __restrict__ out) {
    int b = blockIdx.x, t = threadIdx.x;
    int flag = *flagp;
    int lane = t & 63;

    __shared__ float4 red4[2048];          // 32 KB: cbuf[h][1000], then j-reduce scratch
    float* cbuf = (float*)red4;
    __shared__ float wemb_s[HH][DD];       // 4 KB
    __shared__ float small[3 * DD];        // hl / gl / g2
    __shared__ float zl[HH];

    // A lane-distributed: lane l holds A[l][h] (alo) and A[64+l][h] (ahi)
    const float* Ab = Afold + (size_t)b * 1024;
    float alo[8], ahi[8];
#pragma unroll
    for (int h = 0; h < HH; ++h) {
        alo[h] = Ab[lane * 8 + h];
        ahi[h] = Ab[(64 + lane) * 8 + h];
    }

    const float4* embB4 = (const float4*)(emb + (size_t)b * NN * DD);
    const int mbase = b * NN;

    // ---- phase 1: compat for all rows, straight from global ----
    for (int s = 0; s < 4; ++s) {
        int r = t + s * 256;
        if (r < NN) {
            const float4* row = embB4 + (size_t)r * 32;
            float acc[8] = {0.f, 0.f, 0.f, 0.f, 0.f, 0.f, 0.f, 0.f};
#pragma unroll
            for (int k = 0; k < 16; ++k) {         // c = 0..63
                float4 e = row[k];
                int c = k * 4;
#pragma unroll
                for (int h = 0; h < HH; ++h)
                    acc[h] += e.x * rdl(alo[h], c) + e.y * rdl(alo[h], c + 1)
                            + e.z * rdl(alo[h], c + 2) + e.w * rdl(alo[h], c + 3);
            }
#pragma unroll
            for (int k = 16; k < 32; ++k) {        // c = 64..127
                float4 e = row[k];
                int c = k * 4 - 64;
#pragma unroll
                for (int h = 0; h < HH; ++h)
                    acc[h] += e.x * rdl(ahi[h], c) + e.y * rdl(ahi[h], c + 1)
                            + e.z * rdl(ahi[h], c + 2) + e.w * rdl(ahi[h], c + 3);
            }
            bool feas = mask_feasible(mask, flag, mbase + r);
#pragma unroll
            for (int h = 0; h < HH; ++h)
                cbuf[h * NN + r] = feas ? acc[h] : -INFINITY;
        }
    }
    __syncthreads();
    // ---- phase 2: softmax per head (32 lanes per head), p left unnormalized ----
    {
        int h = t >> 5, l32 = t & 31;
        float* xr = cbuf + h * NN;
        float m = -INFINITY;
        for (int n = l32; n < NN; n += 32) m = fmaxf(m, xr[n]);
#pragma unroll
        for (int off = 1; off < 32; off <<= 1) m = fmaxf(m, __shfl_xor(m, off, 32));
        float z = 0.f;
        for (int n = l32; n < NN; n += 32) {
            float p = __expf(xr[n] - m);   // exp(-inf - m) = 0 for masked
            xr[n] = p;
            z += p;
        }
#pragma unroll
        for (int off = 1; off < 32; off <<= 1) z += __shfl_xor(z, off, 32);
        if (l32 == 0) zl[h] = z;
    }
    __syncthreads();
    // ---- phase 3: accumulate wemb from global (coalesced), p via LDS broadcast ----
    int c4 = t & 31, jr = t >> 5;
    {
        float4 wacc[8];
#pragma unroll
        for (int h = 0; h < HH; ++h) wacc[h] = make_float4(0.f, 0.f, 0.f, 0.f);
        for (int nn = jr; nn < NN; nn += 8) {
            float4 e = embB4[(size_t)nn * 32 + c4];
            float p0 = cbuf[0 * NN + nn], p1 = cbuf[1 * NN + nn];
            float p2 = cbuf[2 * NN + nn], p3 = cbuf[3 * NN + nn];
            float p4 = cbuf[4 * NN + nn], p5 = cbuf[5 * NN + nn];
            float p6 = cbuf[6 * NN + nn], p7 = cbuf[7 * NN + nn];
            wacc[0].x += p0 * e.x; wacc[0].y += p0 * e.y; wacc[0].z += p0 * e.z; wacc[0].w += p0 * e.w;
            wacc[1].x += p1 * e.x; wacc[1].y += p1 * e.y; wacc[1].z += p1 * e.z; wacc[1].w += p1 * e.w;
            wacc[2].x += p2 * e.x; wacc[2].y += p2 * e.y; wacc[2].z += p2 * e.z; wacc[2].w += p2 * e.w;
            wacc[3].x += p3 * e.x; wacc[3].y += p3 * e.y; wacc[3].z += p3 * e.z; wacc[3].w += p3 * e.w;
            wacc[4].x += p4 * e.x; wacc[4].y += p4 * e.y; wacc[4].z += p4 * e.z; wacc[4].w += p4 * e.w;
            wacc[5].x += p5 * e.x; wacc[5].y += p5 * e.y; wacc[5].z += p5 * e.z; wacc[5].w += p5 * e.w;
            wacc[6].x += p6 * e.x; wacc[6].y += p6 * e.y; wacc[6].z += p6 * e.z; wacc[6].w += p6 * e.w;
            wacc[7].x += p7 * e.x; wacc[7].y += p7 * e.y; wacc[7].z += p7 * e.z; wacc[7].w += p7 * e.w;
        }
        __syncthreads();   // cbuf reads done; red4 region can be overwritten
#pragma unroll
        for (int h = 0; h < HH; ++h) red4[(jr * 32 + c4) * 8 + h] = wacc[h];
    }
    __syncthreads();
    // ---- j-reduce + normalize -> wemb_s ----
    {
        int cc = t >> 3, hh = t & 7;
        float4 s = make_float4(0.f, 0.f, 0.f, 0.f);
#pragma unroll
        for (int jj = 0; jj < 8; ++jj) {
            float4 v = red4[(jj * 32 + cc) * 8 + hh];
            s.x += v.x; s.y += v.y; s.z += v.z; s.w += v.w;
        }
        float inv = 1.0f / zl[hh];
        s.x *= inv; s.y *= inv; s.z *= inv; s.w *= inv;
        *(float4*)&wemb_s[hh][cc * 4] = s;
    }
    __syncthreads();
    // ---- glimpse tail ----
    if (t < 128) {
        int h = t >> 4;
        float a = 0.f;
        for (int c = 0; c < DD; ++c) a += wemb_s[h][c] * W_node[(size_t)c * 384 + 128 + t];
        small[t] = a;                          // hl
    }
    __syncthreads();
    if (t < 128) {
        float g = 0.f;
        for (int k = 0; k < DD; ++k) g += small[k] * W_out[k * DD + t];
        small[128 + t] = g;                    // gl
    }
    __syncthreads();
    if (t < 128) {
        float a3 = 0.f;
        const float* wr = W_node + (size_t)t * 384 + 256;   // Wl row t
        for (int d = 0; d < DD; ++d) a3 += wr[d] * small[128 + d];
        small[256 + t] = a3;                   // g2
    }
    __syncthreads();
    // ---- logits tail ----
    const float4* g2v = (const float4*)&small[256];
    for (int r = t; r < NN; r += 256) {
        const float4* row = embB4 + (size_t)r * 32;
        float acc = 0.f;
#pragma unroll 8
        for (int k = 0; k < 32; ++k) {
            float4 e = row[k], g = g2v[k];
            acc += e.x * g.x + e.y * g.y + e.z * g.z + e.w * g.w;
        }
        bool feas = mask_feasible(mask, flag, mbase + r);
        out[(size_t)mbase + r] = feas ? (10.0f * tanhf(acc * 0.08838834764831845f)) : -1.0e30f;
    }
}

extern "C" void kernel_launch(void* const* d_in, const int* in_sizes, int n_in,
                              void* d_out, int out_size, void* d_ws, size_t ws_size,
                              hipStream_t stream) {
    (void)in_sizes; (void)n_in; (void)out_size; (void)ws_size;
    const float* emb     = (const float*)d_in[0];
    const float* ctx     = (const float*)d_in[1];
    const float* W_node  = (const float*)d_in[2];
    const float* W_fixed = (const float*)d_in[3];
    const float* W_step  = (const float*)d_in[4];
    const float* W_out   = (const float*)d_in[5];
    const void*  mask    = d_in[6];
    float* out = (float*)d_out;

    char* ws = (char*)d_ws;
    int*   flag  = (int*)(ws + 0);
    float* Afold = (float*)(ws + WS_AFOLD);

    k0_detect<<<1, 64, 0, stream>>>((const unsigned int*)mask, flag);
    kA_meanfold<<<BB, 512, 0, stream>>>(emb, ctx, W_fixed, W_step, W_node, Afold);
    kB_attn<<<BB, 256, 0, stream>>>(emb, Afold, mask, flag, W_node, W_out, out);
}